// Round 1
// baseline (355.191 us; speedup 1.0000x reference)
//
#include <hip/hip_runtime.h>
#include <hip/hip_fp16.h>

// 3-layer gather-GEMM GNN (N=262144, K=8, 16->128->128->16), f16 MFMA.
// Round 13: layer1p occupancy push. The r12 kernel was latency-bound at
// 3 waves/SIMD (~160 unified regs). Changes, all register-motivated:
//   * gather path now uses global_load_lds width=16 with pre-swizzled
//     per-lane GLOBAL source (linear LDS dest decodes off16: seg=wave*4+i,
//     row=(lane&48)|((lane&15)^(wave*4+i))) -> ga ring + ds_writes deleted.
//   * invd scale moved AFTER the LDS fragment read (a *= invF[m][nb]) —
//     bit-identical f16 multiply, required since global_load_lds bypasses
//     VGPRs.
//   * B prefetch ring halved: hold 2 k-steps + next half (16+16 regs
//     instead of 32+32). W1f is L2-resident so half-phase distance covers.
//   * roff[4][4] -> roff4[4] + m*128 immediate.
//   * __launch_bounds__(256, 4): 4 blocks/CU (LDS 128 KB), 16 waves/CU.
// MFMA accumulation order over (nb,ks) unchanged -> outputs bit-identical.
//
// Workspace: ws = h1 (64 MiB) + P (64 MiB) = 128 MiB exactly. invd/h16/Wf live
// in d_out scratch; invd is d2d-copied into dead h1 before the reduce (which
// writes d_out).

typedef _Float16 f16x8 __attribute__((ext_vector_type(8)));
typedef float f32x4 __attribute__((ext_vector_type(4)));

#define NNODES 262144

__device__ __forceinline__ void gload_lds16(const __half* g, __half* l) {
    __builtin_amdgcn_global_load_lds(
        (const __attribute__((address_space(1))) unsigned int*)g,
        (__attribute__((address_space(3))) unsigned int*)l, 16, 0, 0);
}

__global__ __launch_bounds__(256) void conv_h_kernel(const float* __restrict__ h,
                                                     __half* __restrict__ h16, int n) {
    int i = blockIdx.x * 256 + threadIdx.x;
    if (i < n) h16[i] = __float2half(h[i]);
}

__global__ __launch_bounds__(256) void prep_edges_kernel(const float* __restrict__ pos,
                                                         const int* __restrict__ nbr,
                                                         __half* __restrict__ invd, int n_edges) {
    int e = blockIdx.x * 256 + threadIdx.x;
    if (e >= n_edges) return;
    int i = e >> 3;
    int n = nbr[e];
    float dx = pos[i * 3 + 0] - pos[n * 3 + 0];
    float dy = pos[i * 3 + 1] - pos[n * 3 + 1];
    float dz = pos[i * 3 + 2] - pos[n * 3 + 2];
    float d = sqrtf(dx * dx + dy * dy + dz * dz);
    if (d == 0.0f) d = 0.5f;                       // reference: where(dist==0, 0.5, dist)
    invd[e] = __float2half((1.0f / d) * 0.00390625f);  // prescale 1/256
}

// Pre-shuffle W [KT][FO] (row-major f32) into MFMA B-fragment order:
// Wf[((s*NT + t)*64 + lane)*8 + j] = W[s*32 + (lane>>4)*8 + j][t*16 + (lane&15)]
__global__ __launch_bounds__(256) void shuffle_w_kernel(const float* __restrict__ W,
                                                        __half* __restrict__ Wf,
                                                        int KT, int FO) {
    int e = blockIdx.x * 256 + threadIdx.x;
    if (e >= KT * FO) return;
    int j = e & 7;
    int lane = (e >> 3) & 63;
    int rest = e >> 9;
    int NT = FO >> 4;
    int t = rest % NT;
    int s = rest / NT;
    int k = s * 32 + (lane >> 4) * 8 + j;
    int n = t * 16 + (lane & 15);
    Wf[e] = __float2half(W[k * FO + n]);
}

// Fragment-order for the STACKED W2: W2s[k][t*16+c] = W2[t*128+k][c]
// (W2 row-major [1024][16]; KT=128, FO=128 -> NT=8).
__global__ __launch_bounds__(256) void shuffle_w2s_kernel(const float* __restrict__ W2,
                                                          __half* __restrict__ Wf) {
    int e = blockIdx.x * 256 + threadIdx.x;
    if (e >= 128 * 128) return;
    int j = e & 7;
    int lane = (e >> 3) & 63;
    int rest = e >> 9;
    int t = rest % 8;
    int s = rest / 8;
    int k = s * 32 + (lane >> 4) * 8 + j;
    Wf[e] = __float2half(W2[(size_t)(t * 128 + k) * 16 + (lane & 15)]);
}

// ---------------- L0: F_IN=16, F_OUT=128, 128 rows/block ----------------
__global__ __launch_bounds__(256) void layer0_kernel(
    const __half* __restrict__ hprev, const __half* __restrict__ invd,
    const int* __restrict__ nbr, const __half* __restrict__ Wf,
    const float* __restrict__ bias, __half* __restrict__ outp) {
    __shared__ __align__(16) __half Bs[16384];  // 32 KB weights, staged once

    const int tid = threadIdx.x;
    const int wave = tid >> 6;
    const int lane = tid & 63;
    const int quad = lane >> 4;
    const int lmod = lane & 15;
    const int mbase = blockIdx.x * 128 + wave * 16 + lmod;

    int idx[2][8];
    f16x8 invr[2];
#pragma unroll
    for (int mt = 0; mt < 2; ++mt) {
        const int m = mbase + mt * 64;
        const int4* nrow = (const int4*)(nbr + (size_t)m * 8);
        const int4 iA = nrow[0];
        const int4 iB = nrow[1];
        idx[mt][0] = iA.x; idx[mt][1] = iA.y; idx[mt][2] = iA.z; idx[mt][3] = iA.w;
        idx[mt][4] = iB.x; idx[mt][5] = iB.y; idx[mt][6] = iB.z; idx[mt][7] = iB.w;
        invr[mt] = *(const f16x8*)(invd + (size_t)m * 8);
    }

    f32x4 acc[2][8];
#pragma unroll
    for (int mt = 0; mt < 2; ++mt)
#pragma unroll
        for (int t = 0; t < 8; ++t) acc[mt][t] = f32x4{0.f, 0.f, 0.f, 0.f};

    {
        const uint4* src = (const uint4*)Wf;
        uint4* dst = (uint4*)Bs;
#pragma unroll
        for (int i = 0; i < 8; ++i) dst[i * 256 + tid] = src[i * 256 + tid];
    }
    __syncthreads();

#pragma unroll
    for (int s = 0; s < 4; ++s) {
        const int nb = 2 * s + (quad >> 1);
        f16x8 as[2];
#pragma unroll
        for (int mt = 0; mt < 2; ++mt) {
            f16x8 av = *(const f16x8*)(hprev + (size_t)idx[mt][nb] * 16 + (quad & 1) * 8);
            as[mt] = av * invr[mt][nb];
        }
#pragma unroll
        for (int t = 0; t < 8; ++t) {
            f16x8 b = *(const f16x8*)(Bs + ((size_t)(s * 8 + t) * 64 + lane) * 8);
#pragma unroll
            for (int mt = 0; mt < 2; ++mt)
                acc[mt][t] = __builtin_amdgcn_mfma_f32_16x16x32_f16(as[mt], b, acc[mt][t], 0, 0, 0);
        }
    }

#pragma unroll
    for (int mt = 0; mt < 2; ++mt) {
        const int rbase = blockIdx.x * 128 + mt * 64 + wave * 16 + quad * 4;
#pragma unroll
        for (int t = 0; t < 8; ++t) {
            const int col = t * 16 + lmod;
            const float bv = bias[col];
#pragma unroll
            for (int rr = 0; rr < 4; ++rr) {
                float v = acc[mt][t][rr] * 256.0f + bv;
                outp[(size_t)(rbase + rr) * 128 + col] = __float2half(v);
            }
        }
    }
}

// ------- L1+P: F_IN=128, F_OUT=128, 64 rows/block, fused P projection -------
// LDS: seg-major + XOR swizzle, 16B granules: off16(seg,row) =
//   seg*64 + (row & ~15) + ((row ^ seg) & 15)   -> spans [0, 1024) granules.
__device__ __forceinline__ int off16(int seg, int row) {
    return seg * 64 + (row & ~15) + ((row ^ seg) & 15);
}

__global__ __launch_bounds__(256, 4) void layer1p_kernel(
    const __half* __restrict__ hprev, const __half* __restrict__ invd,
    const int* __restrict__ nbr, const __half* __restrict__ Wf,
    const __half* __restrict__ Wf2s, const float* __restrict__ bias,
    __half* __restrict__ Pout) {
    __shared__ __align__(16) __half As[2][8192];  // 2 x 1024 granules x 16B = 32 KB

    const int tid = threadIdx.x;
    const int wave = tid >> 6;
    const int lane = tid & 63;
    const int quad = lane >> 4;
    const int lmod = lane & 15;
    const int rowblk = blockIdx.x * 64;

    // global_load_lds writes LDS linearly: granule g = wave*256 + i*64 + lane.
    // Inverting off16: seg = g>>6 = wave*4+i (wave-uniform per issue),
    // row = (lane&48) | ((lane&15) ^ (wave*4+i)).  Each thread gathers for
    // its 4 decoded rows.
    int grow2[4];
#pragma unroll
    for (int i = 0; i < 4; ++i) {
        const int row = (lane & 48) | ((lane & 15) ^ (wave * 4 + i));
        grow2[i] = rowblk + row;
    }

    // Neighbor-index ring: idxA (nb0, preloop issue), idxB (nb1),
    // idxR[0]=nb2; refill at iter nb (nb<5): idxR[(nb+1)&1] = nb+3.
    int idxA[4], idxB[4], idxR[2][4];
#pragma unroll
    for (int i = 0; i < 4; ++i) {
        const int* nb_ = nbr + (size_t)grow2[i] * 8;
        idxA[i] = nb_[0];
        idxB[i] = nb_[1];
        idxR[0][i] = nb_[2];
    }

    // Frag-scale factors: invF[m][nb] = invd_pre[rowblk + m*16 + lmod][nb]
    // (A-fragment row for (m,*) is m*16+lmod on every lane).
    f16x8 invF[4];
#pragma unroll
    for (int m = 0; m < 4; ++m)
        invF[m] = *(const f16x8*)(invd + (size_t)(rowblk + m * 16 + lmod) * 8);

    // ds_read offsets (halves): granule off16(ks*4+quad, m*16+lmod) =
    // roff4[ks]/8 + m*16  ->  half offset roff4[ks] + m*128 (m folds to imm).
    int roff4[4];
#pragma unroll
    for (int ks = 0; ks < 4; ++ks) {
        const int seg = ks * 4 + quad;
        roff4[ks] = (seg * 64 + ((lmod ^ seg) & 15)) * 8;
    }

    // This wave's two output col-tiles: t = wave*2 + tl.
    const __half* WfB = Wf + ((size_t)(wave * 2) * 64 + lane) * 8;

    // Half-width B ring: phase p = nb*2 + h covers s = 2p, 2p+1.
    f16x8 Bc[2][2], Bn[2][2];
#pragma unroll
    for (int ks2 = 0; ks2 < 2; ++ks2)
#pragma unroll
        for (int tl = 0; tl < 2; ++tl)
            Bc[ks2][tl] = *(const f16x8*)(WfB + (size_t)(ks2 * 8 + tl) * 512);

    // Issue gathers for nb=0 into As[0] (drained by the barrier below).
#pragma unroll
    for (int i = 0; i < 4; ++i)
        gload_lds16(hprev + (size_t)idxA[i] * 128 + (wave * 4 + i) * 8,
                    &As[0][(size_t)(wave * 256 + i * 64) * 8]);

    f32x4 acc[4][2];
#pragma unroll
    for (int m = 0; m < 4; ++m) { acc[m][0] = f32x4{0.f,0.f,0.f,0.f}; acc[m][1] = f32x4{0.f,0.f,0.f,0.f}; }

    __syncthreads();

#pragma unroll
    for (int nb = 0; nb < 8; ++nb) {
        const int cur = nb & 1;
        // Issue gathers for neighbor nb+1 into As[cur^1] (in flight across
        // this iteration's compute; drained by the trailing barrier).
        if (nb < 7) {
#pragma unroll
            for (int i = 0; i < 4; ++i) {
                const int id = (nb == 0) ? idxB[i] : idxR[(nb + 1) & 1][i];
                gload_lds16(hprev + (size_t)id * 128 + (wave * 4 + i) * 8,
                            &As[cur ^ 1][(size_t)(wave * 256 + i * 64) * 8]);
            }
        }
        // Ring refill: neighbor nb+3 into slot (nb+1)&1 (its prior occupant
        // nb+1 was just issued above).
        if (nb < 5) {
#pragma unroll
            for (int i = 0; i < 4; ++i)
                idxR[(nb + 1) & 1][i] = nbr[(size_t)grow2[i] * 8 + nb + 3];
        }
        // Compute from As[cur]: two B half-phases (ks = h*2 + ks2).
#pragma unroll
        for (int h = 0; h < 2; ++h) {
            const int p = nb * 2 + h;
            if (p < 15) {
#pragma unroll
                for (int ks2 = 0; ks2 < 2; ++ks2)
#pragma unroll
                    for (int tl = 0; tl < 2; ++tl)
                        Bn[ks2][tl] = *(const f16x8*)(WfB + (size_t)(((p + 1) * 2 + ks2) * 8 + tl) * 512);
            }
#pragma unroll
            for (int m = 0; m < 4; ++m) {
#pragma unroll
                for (int ks2 = 0; ks2 < 2; ++ks2) {
                    const int ks = h * 2 + ks2;
                    f16x8 a = *(const f16x8*)(&As[cur][roff4[ks] + m * 128]);
                    a = a * invF[m][nb];
                    acc[m][0] = __builtin_amdgcn_mfma_f32_16x16x32_f16(a, Bc[ks2][0], acc[m][0], 0, 0, 0);
                    acc[m][1] = __builtin_amdgcn_mfma_f32_16x16x32_f16(a, Bc[ks2][1], acc[m][1], 0, 0, 0);
                }
            }
#pragma unroll
            for (int ks2 = 0; ks2 < 2; ++ks2) {
                Bc[ks2][0] = Bn[ks2][0];
                Bc[ks2][1] = Bn[ks2][1];
            }
        }
        if (nb < 7) __syncthreads();
    }

    // ---- Fused epilogue: h2 = leaky(acc*256 + b1) -> LDS (swizzled) ----
    // As[0] is free: its last reader was nb=6's compute, before the last
    // barrier (and its last gather drained at iter 5's barrier). h2 tile =
    // 64 rows x 128 cols, element (row,col) at granule off16(col>>3, row),
    // half (col&7).
    __half* As0 = &As[0][0];
#pragma unroll
    for (int m = 0; m < 4; ++m) {
#pragma unroll
        for (int tl = 0; tl < 2; ++tl) {
            const int col = wave * 32 + tl * 16 + lmod;
            const float bv = bias[col];
            const int sg = col >> 3;
            const int jj = col & 7;
#pragma unroll
            for (int rr = 0; rr < 4; ++rr) {
                const int row = m * 16 + quad * 4 + rr;
                float v = acc[m][tl][rr] * 256.0f + bv;
                v = (v >= 0.f) ? v : 0.01f * v;
                As0[off16(sg, row) * 8 + jj] = __float2half(v);
            }
        }
    }
    __syncthreads();

    // ---- P = h2 @ W2s (K=128, 4 k-steps); wave owns col-tiles wave*2+tl ----
    const __half* WfB2 = Wf2s + ((size_t)(wave * 2) * 64 + lane) * 8;
    f16x8 B2[4][2];
#pragma unroll
    for (int ks = 0; ks < 4; ++ks)
#pragma unroll
        for (int tl = 0; tl < 2; ++tl)
            B2[ks][tl] = *(const f16x8*)(WfB2 + (size_t)(ks * 8 + tl) * 512);

    f32x4 acc2[4][2];
#pragma unroll
    for (int m = 0; m < 4; ++m) { acc2[m][0] = f32x4{0.f,0.f,0.f,0.f}; acc2[m][1] = f32x4{0.f,0.f,0.f,0.f}; }
#pragma unroll
    for (int m = 0; m < 4; ++m) {
#pragma unroll
        for (int ks = 0; ks < 4; ++ks) {
            f16x8 a2 = *(const f16x8*)(&As0[roff4[ks] + m * 128]);
            acc2[m][0] = __builtin_amdgcn_mfma_f32_16x16x32_f16(a2, B2[ks][0], acc2[m][0], 0, 0, 0);
            acc2[m][1] = __builtin_amdgcn_mfma_f32_16x16x32_f16(a2, B2[ks][1], acc2[m][1], 0, 0, 0);
        }
    }

    // ---- write P (fp16, true scale) ----
#pragma unroll
    for (int m = 0; m < 4; ++m) {
#pragma unroll
        for (int tl = 0; tl < 2; ++tl) {
            const int col = wave * 32 + tl * 16 + lmod;
#pragma unroll
            for (int rr = 0; rr < 4; ++rr) {
                const int grow = rowblk + m * 16 + quad * 4 + rr;
                Pout[(size_t)grow * 128 + col] = __float2half(acc2[m][tl][rr]);
            }
        }
    }
}

// ---------------- Reduce: out[i] = 256*sum_k invd[i,k]*P[nbr[i,k]][k*16..]+b2
__global__ __launch_bounds__(256) void reduce_kernel(
    const __half* __restrict__ P, const __half* __restrict__ invd,
    const int* __restrict__ nbr, const float* __restrict__ b2,
    float* __restrict__ outp) {
    const int d = blockIdx.x * 256 + threadIdx.x;

    const int4* nrow = (const int4*)(nbr + (size_t)d * 8);
    const int4 iA = nrow[0];
    const int4 iB = nrow[1];
    const int idx[8] = {iA.x, iA.y, iA.z, iA.w, iB.x, iB.y, iB.z, iB.w};
    const f16x8 iv = *(const f16x8*)(invd + (size_t)d * 8);

    // Issue all 16 gather loads up front.
    f16x8 lo[8], hi[8];
#pragma unroll
    for (int k = 0; k < 8; ++k) {
        const __half* p = P + (size_t)idx[k] * 128 + k * 16;
        lo[k] = *(const f16x8*)p;
        hi[k] = *(const f16x8*)(p + 8);
    }

    float acc[16];
#pragma unroll
    for (int c = 0; c < 16; ++c) acc[c] = 0.f;
#pragma unroll
    for (int k = 0; k < 8; ++k) {
        const float w = (float)iv[k];
#pragma unroll
        for (int c = 0; c < 8; ++c) {
            acc[c] += w * (float)lo[k][c];
            acc[c + 8] += w * (float)hi[k][c];
        }
    }

    float4 o[4];
#pragma unroll
    for (int q = 0; q < 4; ++q) {
        o[q].x = acc[q * 4 + 0] * 256.0f + b2[q * 4 + 0];
        o[q].y = acc[q * 4 + 1] * 256.0f + b2[q * 4 + 1];
        o[q].z = acc[q * 4 + 2] * 256.0f + b2[q * 4 + 2];
        o[q].w = acc[q * 4 + 3] * 256.0f + b2[q * 4 + 3];
    }
    float4* dst = (float4*)(outp + (size_t)d * 16);
#pragma unroll
    for (int q = 0; q < 4; ++q) dst[q] = o[q];
}

extern "C" void kernel_launch(void* const* d_in, const int* in_sizes, int n_in,
                              void* d_out, int out_size, void* d_ws, size_t ws_size,
                              hipStream_t stream) {
    const float* h   = (const float*)d_in[0];
    const float* pos = (const float*)d_in[1];
    const int*   nbr = (const int*)d_in[2];
    const float* W0  = (const float*)d_in[3];
    const float* b0  = (const float*)d_in[4];
    const float* W1  = (const float*)d_in[5];
    const float* b1  = (const float*)d_in[6];
    const float* W2  = (const float*)d_in[7];
    const float* b2  = (const float*)d_in[8];

    const int N = NNODES;

    // ws: h1 (64 MiB) + P (64 MiB) = 128 MiB exactly.
    char* w = (char*)d_ws;
    __half* h1 = (__half*)w;                               // 67,108,864 B
    __half* P  = (__half*)(w + (size_t)67108864);          // 67,108,864 B
    __half* invd2 = (__half*)w;                            // 4 MiB, into dead h1

    // d_out doubles as scratch until reduce overwrites all of it (16 MiB).
    char* ob = (char*)d_out;
    __half* invd = (__half*)(ob + 0);                      // 4,194,304 B
    __half* h16  = (__half*)(ob + 4194304);                // 8,388,608 B
    __half* W0f  = (__half*)(ob + 12582912);               // 32,768 B
    __half* W1f  = (__half*)(ob + 12615680);               // 262,144 B
    __half* Wf2s = (__half*)(ob + 12877824);               // 32,768 B (end 12,910,592)

    conv_h_kernel<<<(N * 16 + 255) / 256, 256, 0, stream>>>(h, h16, N * 16);
    prep_edges_kernel<<<(N * 8 + 255) / 256, 256, 0, stream>>>(pos, nbr, invd, N * 8);
    shuffle_w_kernel<<<(128 * 128 + 255) / 256, 256, 0, stream>>>(W0, W0f, 128, 128);
    shuffle_w_kernel<<<(1024 * 128 + 255) / 256, 256, 0, stream>>>(W1, W1f, 1024, 128);
    shuffle_w2s_kernel<<<(128 * 128 + 255) / 256, 256, 0, stream>>>(W2, Wf2s);

    layer0_kernel<<<N / 128, 256, 0, stream>>>(h16, invd, nbr, W0f, b0, h1);
    layer1p_kernel<<<N / 64, 256, 0, stream>>>(h1, invd, nbr, W1f, Wf2s, b1, P);

    // h1 is dead now; move invd out of d_out before reduce writes d_out.
    (void)hipMemcpyAsync(invd2, invd, 4194304, hipMemcpyDeviceToDevice, stream);

    reduce_kernel<<<N / 256, 256, 0, stream>>>(P, invd2, nbr, b2, (float*)d_out);
}

// Round 2
// 326.213 us; speedup vs baseline: 1.0888x; 1.0888x over previous
//
#include <hip/hip_runtime.h>
#include <hip/hip_fp16.h>

// 3-layer gather-GEMM GNN (N=262144, K=8, 16->128->128->16), f16 MFMA.
// Round 14: restore r12's reg-staged gather ring (global->VGPR loads cross
// __syncthreads barriers -> true 2-deep pipeline; r13's global_load_lds was
// force-drained by every barrier = depth 0, regressed), while keeping r13's
// register trims so the kernel fits 4 blocks/CU:
//   * ga[2][4] gather ring + ds_write staging (r12) — the pipeline.
//   * half-width B prefetch ring (Bc/Bn 2x2, 32 regs vs r12's 64); per-acc
//     ks order unchanged (0,1,2,3 per nb) -> bit-identical accumulation.
//   * roff[4][4] -> roff4[4] + m*128 immediate.
//   * invS[4] (16 regs) -> on-demand 2B scalar loads at staging (L1-hot row),
//     same f16 multiply -> bit-identical.
//   * idx ring 16 -> 8 regs (2-slot idxQ, refill 2 iters ahead).
//   * nbr/invd addressed via one base pointer + immediate offsets.
//   * __launch_bounds__(256, 4): reg cap 128 unified, LDS 4x32KB = 128 KB.
//
// Workspace: ws = h1 (64 MiB) + P (64 MiB) = 128 MiB exactly. invd/h16/Wf live
// in d_out scratch; invd is d2d-copied into dead h1 before the reduce (which
// writes d_out).

typedef _Float16 f16x8 __attribute__((ext_vector_type(8)));
typedef float f32x4 __attribute__((ext_vector_type(4)));

#define NNODES 262144

__global__ __launch_bounds__(256) void conv_h_kernel(const float* __restrict__ h,
                                                     __half* __restrict__ h16, int n) {
    int i = blockIdx.x * 256 + threadIdx.x;
    if (i < n) h16[i] = __float2half(h[i]);
}

__global__ __launch_bounds__(256) void prep_edges_kernel(const float* __restrict__ pos,
                                                         const int* __restrict__ nbr,
                                                         __half* __restrict__ invd, int n_edges) {
    int e = blockIdx.x * 256 + threadIdx.x;
    if (e >= n_edges) return;
    int i = e >> 3;
    int n = nbr[e];
    float dx = pos[i * 3 + 0] - pos[n * 3 + 0];
    float dy = pos[i * 3 + 1] - pos[n * 3 + 1];
    float dz = pos[i * 3 + 2] - pos[n * 3 + 2];
    float d = sqrtf(dx * dx + dy * dy + dz * dz);
    if (d == 0.0f) d = 0.5f;                       // reference: where(dist==0, 0.5, dist)
    invd[e] = __float2half((1.0f / d) * 0.00390625f);  // prescale 1/256
}

// Pre-shuffle W [KT][FO] (row-major f32) into MFMA B-fragment order:
// Wf[((s*NT + t)*64 + lane)*8 + j] = W[s*32 + (lane>>4)*8 + j][t*16 + (lane&15)]
__global__ __launch_bounds__(256) void shuffle_w_kernel(const float* __restrict__ W,
                                                        __half* __restrict__ Wf,
                                                        int KT, int FO) {
    int e = blockIdx.x * 256 + threadIdx.x;
    if (e >= KT * FO) return;
    int j = e & 7;
    int lane = (e >> 3) & 63;
    int rest = e >> 9;
    int NT = FO >> 4;
    int t = rest % NT;
    int s = rest / NT;
    int k = s * 32 + (lane >> 4) * 8 + j;
    int n = t * 16 + (lane & 15);
    Wf[e] = __float2half(W[k * FO + n]);
}

// Fragment-order for the STACKED W2: W2s[k][t*16+c] = W2[t*128+k][c]
// (W2 row-major [1024][16]; KT=128, FO=128 -> NT=8).
__global__ __launch_bounds__(256) void shuffle_w2s_kernel(const float* __restrict__ W2,
                                                          __half* __restrict__ Wf) {
    int e = blockIdx.x * 256 + threadIdx.x;
    if (e >= 128 * 128) return;
    int j = e & 7;
    int lane = (e >> 3) & 63;
    int rest = e >> 9;
    int t = rest % 8;
    int s = rest / 8;
    int k = s * 32 + (lane >> 4) * 8 + j;
    Wf[e] = __float2half(W2[(size_t)(t * 128 + k) * 16 + (lane & 15)]);
}

// ---------------- L0: F_IN=16, F_OUT=128, 128 rows/block ----------------
__global__ __launch_bounds__(256) void layer0_kernel(
    const __half* __restrict__ hprev, const __half* __restrict__ invd,
    const int* __restrict__ nbr, const __half* __restrict__ Wf,
    const float* __restrict__ bias, __half* __restrict__ outp) {
    __shared__ __align__(16) __half Bs[16384];  // 32 KB weights, staged once

    const int tid = threadIdx.x;
    const int wave = tid >> 6;
    const int lane = tid & 63;
    const int quad = lane >> 4;
    const int lmod = lane & 15;
    const int mbase = blockIdx.x * 128 + wave * 16 + lmod;

    int idx[2][8];
    f16x8 invr[2];
#pragma unroll
    for (int mt = 0; mt < 2; ++mt) {
        const int m = mbase + mt * 64;
        const int4* nrow = (const int4*)(nbr + (size_t)m * 8);
        const int4 iA = nrow[0];
        const int4 iB = nrow[1];
        idx[mt][0] = iA.x; idx[mt][1] = iA.y; idx[mt][2] = iA.z; idx[mt][3] = iA.w;
        idx[mt][4] = iB.x; idx[mt][5] = iB.y; idx[mt][6] = iB.z; idx[mt][7] = iB.w;
        invr[mt] = *(const f16x8*)(invd + (size_t)m * 8);
    }

    f32x4 acc[2][8];
#pragma unroll
    for (int mt = 0; mt < 2; ++mt)
#pragma unroll
        for (int t = 0; t < 8; ++t) acc[mt][t] = f32x4{0.f, 0.f, 0.f, 0.f};

    {
        const uint4* src = (const uint4*)Wf;
        uint4* dst = (uint4*)Bs;
#pragma unroll
        for (int i = 0; i < 8; ++i) dst[i * 256 + tid] = src[i * 256 + tid];
    }
    __syncthreads();

#pragma unroll
    for (int s = 0; s < 4; ++s) {
        const int nb = 2 * s + (quad >> 1);
        f16x8 as[2];
#pragma unroll
        for (int mt = 0; mt < 2; ++mt) {
            f16x8 av = *(const f16x8*)(hprev + (size_t)idx[mt][nb] * 16 + (quad & 1) * 8);
            as[mt] = av * invr[mt][nb];
        }
#pragma unroll
        for (int t = 0; t < 8; ++t) {
            f16x8 b = *(const f16x8*)(Bs + ((size_t)(s * 8 + t) * 64 + lane) * 8);
#pragma unroll
            for (int mt = 0; mt < 2; ++mt)
                acc[mt][t] = __builtin_amdgcn_mfma_f32_16x16x32_f16(as[mt], b, acc[mt][t], 0, 0, 0);
        }
    }

#pragma unroll
    for (int mt = 0; mt < 2; ++mt) {
        const int rbase = blockIdx.x * 128 + mt * 64 + wave * 16 + quad * 4;
#pragma unroll
        for (int t = 0; t < 8; ++t) {
            const int col = t * 16 + lmod;
            const float bv = bias[col];
#pragma unroll
            for (int rr = 0; rr < 4; ++rr) {
                float v = acc[mt][t][rr] * 256.0f + bv;
                outp[(size_t)(rbase + rr) * 128 + col] = __float2half(v);
            }
        }
    }
}

// ------- L1+P: F_IN=128, F_OUT=128, 64 rows/block, fused P projection -------
// LDS: seg-major + XOR swizzle, 16B granules: off16(seg,row) =
//   seg*64 + (row & ~15) + ((row ^ seg) & 15)   -> spans [0, 1024) granules.
__device__ __forceinline__ int off16(int seg, int row) {
    return seg * 64 + (row & ~15) + ((row ^ seg) & 15);
}

__global__ __launch_bounds__(256, 4) void layer1p_kernel(
    const __half* __restrict__ hprev, const __half* __restrict__ invd,
    const int* __restrict__ nbr, const __half* __restrict__ Wf,
    const __half* __restrict__ Wf2s, const float* __restrict__ bias,
    __half* __restrict__ Pout) {
    __shared__ __align__(16) __half As[2][8192];  // 2 x 1024 granules x 16B = 32 KB

    const int tid = threadIdx.x;
    const int wave = tid >> 6;
    const int lane = tid & 63;
    const int quad = lane >> 4;
    const int lmod = lane & 15;
    const int rowblk = blockIdx.x * 64;
    const int seg = lmod;  // staging: this thread's 16B segment

    // Thread's 4 staged rows: srow(i) = wave*16 + i*4 + quad; global row
    // rbase + i*4 with rbase = rowblk + wave*16 + quad.  nbr/invd rows for
    // (i, nb) sit at base + i*32 + nb -> one base pointer, imm offsets.
    const int rbase = rowblk + wave * 16 + quad;
    const int* nbp = nbr + (size_t)rbase * 8;
    const __half* ivp = invd + (size_t)rbase * 8;

    int soff[4];
#pragma unroll
    for (int i = 0; i < 4; ++i) {
        const int srow = wave * 16 + i * 4 + quad;
        soff[i] = off16(seg, srow) * 8;  // halves
    }

    // Fragment-read offsets (halves): off16(ks*4+quad, m*16+lmod)*8 =
    // roff4[ks] + m*128.
    int roff4[4];
#pragma unroll
    for (int ks = 0; ks < 4; ++ks) {
        const int sg = ks * 4 + quad;
        roff4[ks] = (sg * 64 + ((lmod ^ sg) & 15)) * 8;
    }

    // This wave's two output col-tiles: t = wave*2 + tl.
    const __half* WfB = Wf + ((size_t)(wave * 2) * 64 + lane) * 8;

    // Half-width B ring: phase p = nb*2 + h covers s = 2p, 2p+1.
    f16x8 Bc[2][2], Bn[2][2];
#pragma unroll
    for (int ks2 = 0; ks2 < 2; ++ks2)
#pragma unroll
        for (int tl = 0; tl < 2; ++tl)
            Bc[ks2][tl] = *(const f16x8*)(WfB + (size_t)(ks2 * 8 + tl) * 512);

    // 2-deep gather ring (global->VGPR loads cross barriers) + 2-slot idx ring.
    int idxQ[2][4];
    f16x8 ga[2][4];
    {
        int id0[4], id1[4];
#pragma unroll
        for (int i = 0; i < 4; ++i) id0[i] = nbp[i * 32 + 0];
#pragma unroll
        for (int i = 0; i < 4; ++i)
            ga[0][i] = *(const f16x8*)(hprev + (size_t)id0[i] * 128 + seg * 8);
#pragma unroll
        for (int i = 0; i < 4; ++i) id1[i] = nbp[i * 32 + 1];
#pragma unroll
        for (int i = 0; i < 4; ++i)
            ga[1][i] = *(const f16x8*)(hprev + (size_t)id1[i] * 128 + seg * 8);
#pragma unroll
        for (int i = 0; i < 4; ++i) idxQ[0][i] = nbp[i * 32 + 2];
#pragma unroll
        for (int i = 0; i < 4; ++i) idxQ[1][i] = nbp[i * 32 + 3];
    }

    // Stage neighbor 0 (scaled) into As[0].
#pragma unroll
    for (int i = 0; i < 4; ++i) {
        const _Float16 sc = *(const _Float16*)(ivp + i * 32 + 0);
        f16x8 v = ga[0][i] * sc;
        *(f16x8*)(&As[0][soff[i]]) = v;
    }
    __syncthreads();

    f32x4 acc[4][2];
#pragma unroll
    for (int m = 0; m < 4; ++m) { acc[m][0] = f32x4{0.f,0.f,0.f,0.f}; acc[m][1] = f32x4{0.f,0.f,0.f,0.f}; }

#pragma unroll
    for (int nb = 0; nb < 8; ++nb) {
        const int cur = nb & 1;
        // Issue gathers for neighbor nb+2 into ga[cur] (slot's old data =
        // neighbor nb, staged at end of iter nb-1).  Crosses barriers freely.
        if (nb < 6) {
#pragma unroll
            for (int i = 0; i < 4; ++i)
                ga[cur][i] = *(const f16x8*)(hprev + (size_t)idxQ[cur][i] * 128 + seg * 8);
        }
        // Refill idx ring: neighbor nb+4 into the slot just consumed.
        if (nb < 4) {
#pragma unroll
            for (int i = 0; i < 4; ++i)
                idxQ[cur][i] = nbp[i * 32 + nb + 4];
        }
        // Compute from As[cur]: two B half-phases (ks = h*2 + ks2).
#pragma unroll
        for (int h = 0; h < 2; ++h) {
            const int p = nb * 2 + h;
            if (p < 15) {
#pragma unroll
                for (int ks2 = 0; ks2 < 2; ++ks2)
#pragma unroll
                    for (int tl = 0; tl < 2; ++tl)
                        Bn[ks2][tl] = *(const f16x8*)(WfB + (size_t)(((p + 1) * 2 + ks2) * 8 + tl) * 512);
            }
#pragma unroll
            for (int m = 0; m < 4; ++m) {
#pragma unroll
                for (int ks2 = 0; ks2 < 2; ++ks2) {
                    f16x8 a = *(const f16x8*)(&As[cur][roff4[h * 2 + ks2] + m * 128]);
                    acc[m][0] = __builtin_amdgcn_mfma_f32_16x16x32_f16(a, Bc[ks2][0], acc[m][0], 0, 0, 0);
                    acc[m][1] = __builtin_amdgcn_mfma_f32_16x16x32_f16(a, Bc[ks2][1], acc[m][1], 0, 0, 0);
                }
            }
#pragma unroll
            for (int ks2 = 0; ks2 < 2; ++ks2) {
                Bc[ks2][0] = Bn[ks2][0];
                Bc[ks2][1] = Bn[ks2][1];
            }
        }
        // Stage neighbor nb+1 (scaled) into As[cur^1], then barrier.
        if (nb < 7) {
#pragma unroll
            for (int i = 0; i < 4; ++i) {
                const _Float16 sc = *(const _Float16*)(ivp + i * 32 + nb + 1);
                f16x8 v = ga[(nb + 1) & 1][i] * sc;
                *(f16x8*)(&As[cur ^ 1][soff[i]]) = v;
            }
            __syncthreads();
        }
    }

    // ---- Fused epilogue: h2 = leaky(acc*256 + b1) -> LDS (swizzled) ----
    // As[0] is free: its last reader was nb=6's compute, before the last
    // barrier. h2 tile = 64 rows x 128 cols, element (row,col) at granule
    // off16(col>>3, row), half (col&7).
    __half* As0 = &As[0][0];
#pragma unroll
    for (int m = 0; m < 4; ++m) {
#pragma unroll
        for (int tl = 0; tl < 2; ++tl) {
            const int col = wave * 32 + tl * 16 + lmod;
            const float bv = bias[col];
            const int sg = col >> 3;
            const int jj = col & 7;
#pragma unroll
            for (int rr = 0; rr < 4; ++rr) {
                const int row = m * 16 + quad * 4 + rr;
                float v = acc[m][tl][rr] * 256.0f + bv;
                v = (v >= 0.f) ? v : 0.01f * v;
                As0[off16(sg, row) * 8 + jj] = __float2half(v);
            }
        }
    }
    __syncthreads();

    // ---- P = h2 @ W2s (K=128, 4 k-steps); wave owns col-tiles wave*2+tl ----
    const __half* WfB2 = Wf2s + ((size_t)(wave * 2) * 64 + lane) * 8;
    f16x8 B2[4][2];
#pragma unroll
    for (int ks = 0; ks < 4; ++ks)
#pragma unroll
        for (int tl = 0; tl < 2; ++tl)
            B2[ks][tl] = *(const f16x8*)(WfB2 + (size_t)(ks * 8 + tl) * 512);

    f32x4 acc2[4][2];
#pragma unroll
    for (int m = 0; m < 4; ++m) { acc2[m][0] = f32x4{0.f,0.f,0.f,0.f}; acc2[m][1] = f32x4{0.f,0.f,0.f,0.f}; }
#pragma unroll
    for (int m = 0; m < 4; ++m) {
#pragma unroll
        for (int ks = 0; ks < 4; ++ks) {
            f16x8 a2 = *(const f16x8*)(&As0[roff4[ks] + m * 128]);
            acc2[m][0] = __builtin_amdgcn_mfma_f32_16x16x32_f16(a2, B2[ks][0], acc2[m][0], 0, 0, 0);
            acc2[m][1] = __builtin_amdgcn_mfma_f32_16x16x32_f16(a2, B2[ks][1], acc2[m][1], 0, 0, 0);
        }
    }

    // ---- write P (fp16, true scale) ----
#pragma unroll
    for (int m = 0; m < 4; ++m) {
#pragma unroll
        for (int tl = 0; tl < 2; ++tl) {
            const int col = wave * 32 + tl * 16 + lmod;
#pragma unroll
            for (int rr = 0; rr < 4; ++rr) {
                const int grow = rowblk + m * 16 + quad * 4 + rr;
                Pout[(size_t)grow * 128 + col] = __float2half(acc2[m][tl][rr]);
            }
        }
    }
}

// ---------------- Reduce: out[i] = 256*sum_k invd[i,k]*P[nbr[i,k]][k*16..]+b2
__global__ __launch_bounds__(256) void reduce_kernel(
    const __half* __restrict__ P, const __half* __restrict__ invd,
    const int* __restrict__ nbr, const float* __restrict__ b2,
    float* __restrict__ outp) {
    const int d = blockIdx.x * 256 + threadIdx.x;

    const int4* nrow = (const int4*)(nbr + (size_t)d * 8);
    const int4 iA = nrow[0];
    const int4 iB = nrow[1];
    const int idx[8] = {iA.x, iA.y, iA.z, iA.w, iB.x, iB.y, iB.z, iB.w};
    const f16x8 iv = *(const f16x8*)(invd + (size_t)d * 8);

    // Issue all 16 gather loads up front.
    f16x8 lo[8], hi[8];
#pragma unroll
    for (int k = 0; k < 8; ++k) {
        const __half* p = P + (size_t)idx[k] * 128 + k * 16;
        lo[k] = *(const f16x8*)p;
        hi[k] = *(const f16x8*)(p + 8);
    }

    float acc[16];
#pragma unroll
    for (int c = 0; c < 16; ++c) acc[c] = 0.f;
#pragma unroll
    for (int k = 0; k < 8; ++k) {
        const float w = (float)iv[k];
#pragma unroll
        for (int c = 0; c < 8; ++c) {
            acc[c] += w * (float)lo[k][c];
            acc[c + 8] += w * (float)hi[k][c];
        }
    }

    float4 o[4];
#pragma unroll
    for (int q = 0; q < 4; ++q) {
        o[q].x = acc[q * 4 + 0] * 256.0f + b2[q * 4 + 0];
        o[q].y = acc[q * 4 + 1] * 256.0f + b2[q * 4 + 1];
        o[q].z = acc[q * 4 + 2] * 256.0f + b2[q * 4 + 2];
        o[q].w = acc[q * 4 + 3] * 256.0f + b2[q * 4 + 3];
    }
    float4* dst = (float4*)(outp + (size_t)d * 16);
#pragma unroll
    for (int q = 0; q < 4; ++q) dst[q] = o[q];
}

extern "C" void kernel_launch(void* const* d_in, const int* in_sizes, int n_in,
                              void* d_out, int out_size, void* d_ws, size_t ws_size,
                              hipStream_t stream) {
    const float* h   = (const float*)d_in[0];
    const float* pos = (const float*)d_in[1];
    const int*   nbr = (const int*)d_in[2];
    const float* W0  = (const float*)d_in[3];
    const float* b0  = (const float*)d_in[4];
    const float* W1  = (const float*)d_in[5];
    const float* b1  = (const float*)d_in[6];
    const float* W2  = (const float*)d_in[7];
    const float* b2  = (const float*)d_in[8];

    const int N = NNODES;

    // ws: h1 (64 MiB) + P (64 MiB) = 128 MiB exactly.
    char* w = (char*)d_ws;
    __half* h1 = (__half*)w;                               // 67,108,864 B
    __half* P  = (__half*)(w + (size_t)67108864);          // 67,108,864 B
    __half* invd2 = (__half*)w;                            // 4 MiB, into dead h1

    // d_out doubles as scratch until reduce overwrites all of it (16 MiB).
    char* ob = (char*)d_out;
    __half* invd = (__half*)(ob + 0);                      // 4,194,304 B
    __half* h16  = (__half*)(ob + 4194304);                // 8,388,608 B
    __half* W0f  = (__half*)(ob + 12582912);               // 32,768 B
    __half* W1f  = (__half*)(ob + 12615680);               // 262,144 B
    __half* Wf2s = (__half*)(ob + 12877824);               // 32,768 B (end 12,910,592)

    conv_h_kernel<<<(N * 16 + 255) / 256, 256, 0, stream>>>(h, h16, N * 16);
    prep_edges_kernel<<<(N * 8 + 255) / 256, 256, 0, stream>>>(pos, nbr, invd, N * 8);
    shuffle_w_kernel<<<(128 * 128 + 255) / 256, 256, 0, stream>>>(W0, W0f, 128, 128);
    shuffle_w_kernel<<<(1024 * 128 + 255) / 256, 256, 0, stream>>>(W1, W1f, 1024, 128);
    shuffle_w2s_kernel<<<(128 * 128 + 255) / 256, 256, 0, stream>>>(W2, Wf2s);

    layer0_kernel<<<N / 128, 256, 0, stream>>>(h16, invd, nbr, W0f, b0, h1);
    layer1p_kernel<<<N / 64, 256, 0, stream>>>(h1, invd, nbr, W1f, Wf2s, b1, P);

    // h1 is dead now; move invd out of d_out before reduce writes d_out.
    (void)hipMemcpyAsync(invd2, invd, 4194304, hipMemcpyDeviceToDevice, stream);

    reduce_kernel<<<N / 256, 256, 0, stream>>>(P, invd2, nbr, b2, (float*)d_out);
}